// Round 1
// 396.810 us; speedup vs baseline: 1.0644x; 1.0644x over previous
//
#include <hip/hip_runtime.h>
#include <hip/hip_bf16.h>

// LatentMatrixMemory: M_t = lam*M + (rho*alpha)*(k outer v); r_t = q^T M_t
// B=64, T=2048, DK=DV=128, fp32 in/out. Threshold permits bf16 compute.
//
// Round 4: latency-chain attack.
//  - CT=64 chunks (NCH=32) using overflow-free ratio decays:
//      L2_s = cumsum log2(lam)   (inclusive, per-chunk, 64-lane shfl scan)
//      intra:  S'[t][s] = S[t][s] * exp2(L2_t - L2_s)   (<=1, masked s<=t)
//      inter:  r_t += exp2(L2_t) * (q_t . M)
//      update: M = exp2(L2_end)*M + sum_s k_s (x) [ar_s * exp2(L2_end-L2_s) * v_s]
//    No division by P anywhere -> no clamp pathology at CT=64.
//  - ONE __syncthreads per chunk: wave w owns t-rows [16w,16w+16) for
//    GEMM1/2/3 (no DK split, no Rbuf) and i-rows [32w,32w+32) of M for GEMM4.
//    MhT/VwT/VwTd double-buffered; Sd is wave-private (no barrier needed).
//  - Next-chunk q/v/a/r/lam prefetched to registers, issued right AFTER the
//    barrier (syncthreads drains vmcnt) so latency hides under GEMM3/2/4.
//  - GEMM4 A-operand (k, transposed access) read straight from global/L2:
//    rows are wave-disjoint, each element used once -> LDS staging dropped.
// Grid: 4 DV-splits x 64 batches = 256 blocks; block = 4 waves.

typedef float  f32x4  __attribute__((ext_vector_type(4)));
typedef short  bf16x8 __attribute__((ext_vector_type(8)));

constexpr int B_ = 64, T_ = 2048;
constexpr int NSPLIT = 4;
constexpr int CT = 64;          // chunk length
constexpr int NCH = T_ / CT;    // 32 chunks

__device__ __forceinline__ bf16x8 cvt8(float4 a, float4 b) {
  union { __hip_bfloat162 h2[4]; bf16x8 v; } u;
  u.h2[0] = __float22bfloat162_rn(make_float2(a.x, a.y));
  u.h2[1] = __float22bfloat162_rn(make_float2(a.z, a.w));
  u.h2[2] = __float22bfloat162_rn(make_float2(b.x, b.y));
  u.h2[3] = __float22bfloat162_rn(make_float2(b.z, b.w));
  return u.v;
}

__device__ __forceinline__ float fexp2(float x) {
#if defined(__has_builtin)
#if __has_builtin(__builtin_amdgcn_exp2f)
  return __builtin_amdgcn_exp2f(x);
#else
  return exp2f(x);
#endif
#else
  return exp2f(x);
#endif
}

__device__ __forceinline__ float flog2(float x) {
#if defined(__has_builtin)
#if __has_builtin(__builtin_amdgcn_logf)
  return __builtin_amdgcn_logf(x);   // v_log_f32 is log2
#else
  return log2f(x);
#endif
#else
  return log2f(x);
#endif
}

#define MFMA(a, b, c) __builtin_amdgcn_mfma_f32_16x16x32_bf16((a), (b), (c), 0, 0, 0)

__global__ __launch_bounds__(256, 1) void lmm_ct64(
    const float* __restrict__ q_g, const float* __restrict__ k_g,
    const float* __restrict__ v_g, const float* __restrict__ a_g,
    const float* __restrict__ r_g, const float* __restrict__ l_g,
    const float* __restrict__ m0_g, float* __restrict__ out_g)
{
  const int split = blockIdx.x;
  const int b     = blockIdx.y;
  const int tid   = threadIdx.x;
  const int w     = tid >> 6;        // wave 0..3
  const int lane  = tid & 63;
  const int m     = lane & 15;       // MFMA row/col-in-tile
  const int quad  = lane >> 4;
  const int jbase = split * 32;

  // Double-buffered cross-wave LDS (row strides 16B-aligned, odd-ish in banks):
  __shared__ __align__(16) __hip_bfloat16 MhT [2][32][136]; // bf16(M)^T [j][i]
  __shared__ __align__(16) __hip_bfloat16 VwT [2][32][72];  // (ar*v)^T  [j][s]
  __shared__ __align__(16) __hip_bfloat16 VwTd[2][32][72];  // (ar*ratio*v)^T
  // wave-private (single-buffered, same-wave RAW/WAR only):
  __shared__ __align__(16) __hip_bfloat16 Sd[4][16][72];    // decayed scores [t][s]

  const float* qb = q_g + (size_t)b * T_ * 128;
  const float* kb = k_g + (size_t)b * T_ * 128;
  const float* vb = v_g + (size_t)b * T_ * 128;
  const float* ab = a_g + (size_t)b * T_;
  const float* rb = r_g + (size_t)b * T_;
  const float* lb = l_g + (size_t)b * T_;
  float*       ob = out_g + (size_t)b * T_ * 128;

  // ---- M accumulator (fp32 resident): rows w*32..+32, cols jbase..+32 ----
  f32x4 M[2][2];
  #pragma unroll
  for (int it = 0; it < 2; ++it)
    #pragma unroll
    for (int jt = 0; jt < 2; ++jt)
      #pragma unroll
      for (int r = 0; r < 4; ++r)
        M[it][jt][r] =
            m0_g[((size_t)b * 128 + w * 32 + it * 16 + quad * 4 + r) * 128 +
                 jbase + jt * 16 + m];

  // ---- register prefetch state + chunk-0 fill ----
  const int jv = tid & 31;   // V staging column
  const int s8 = tid >> 5;   // V staging 8-row s-block
  float4 qpre[4][2];
  float  vpre[8];
  float  lpre, apre, rpre;
  #pragma unroll
  for (int ks = 0; ks < 4; ++ks) {
    const float* p = qb + (size_t)(w * 16 + m) * 128 + ks * 32 + quad * 8;
    qpre[ks][0] = *(const float4*)p;
    qpre[ks][1] = *(const float4*)(p + 4);
  }
  #pragma unroll
  for (int rep = 0; rep < 8; ++rep)
    vpre[rep] = vb[(size_t)(s8 * 8 + rep) * 128 + jbase + jv];
  lpre = lb[lane]; apre = ab[lane]; rpre = rb[lane];

  #pragma unroll 2
  for (int ch = 0; ch < NCH; ++ch) {
    const int t0  = ch * CT;
    const int tn  = (ch + 1 < NCH) ? t0 + CT : t0;  // clamped prefetch base
    const int buf = ch & 1;

    // ================= phase A (stage buf, all pre-barrier) =================
    // decay prefix in log2 space, redundant 64-lane scan per wave
    float x = flog2(fmaxf(lpre, 1e-20f));
    #pragma unroll
    for (int d = 1; d < 64; d <<= 1) {
      const float o = __shfl_up(x, d, 64);
      if (lane >= d) x += o;
    }
    const float L2    = x;                    // lane l holds cumsum through s=l
    const float L2end = __shfl(L2, 63, 64);
    const float arp   = apre * rpre;          // grab before prefetch overwrite

    // q fragments (A for GEMM1 and GEMM3)
    bf16x8 qf[4];
    #pragma unroll
    for (int ks = 0; ks < 4; ++ks) qf[ks] = cvt8(qpre[ks][0], qpre[ks][1]);

    // GEMM4 A-operand: own i-rows of k, transposed access, issue early
    float k4[2][2][8];
    #pragma unroll
    for (int kk = 0; kk < 2; ++kk)
      #pragma unroll
      for (int it = 0; it < 2; ++it)
        #pragma unroll
        for (int u = 0; u < 8; ++u)
          k4[kk][it][u] = kb[(size_t)(t0 + kk * 32 + quad * 8 + u) * 128 +
                             w * 32 + it * 16 + m];

    // GEMM1: S[own 16 t][64 s] over full DK=128, B-frags straight from L2
    f32x4 S[4] = {{0.f,0.f,0.f,0.f},{0.f,0.f,0.f,0.f},
                  {0.f,0.f,0.f,0.f},{0.f,0.f,0.f,0.f}};
    #pragma unroll
    for (int sb = 0; sb < 4; ++sb)
      #pragma unroll
      for (int ks = 0; ks < 4; ++ks) {
        const float* p = kb + (size_t)(t0 + sb * 16 + m) * 128 + ks * 32 + quad * 8;
        const bf16x8 bfr = cvt8(*(const float4*)p, *(const float4*)(p + 4));
        S[sb] = MFMA(qf[ks], bfr, S[sb]);
      }

    // decay + causal mask -> Sd (wave-private; exp2 args <= 0, no overflow)
    const int tl0 = w * 16 + quad * 4;
    float tl[4];
    #pragma unroll
    for (int r = 0; r < 4; ++r) tl[r] = __shfl(L2, tl0 + r, 64);
    #pragma unroll
    for (int sb = 0; sb < 4; ++sb) {
      const int   sl_i = sb * 16 + m;
      const float sl   = __shfl(L2, sl_i, 64);
      #pragma unroll
      for (int r = 0; r < 4; ++r) {
        const float dv = (sl_i <= tl0 + r) ? S[sb][r] * fexp2(tl[r] - sl) : 0.f;
        Sd[w][quad * 4 + r][sl_i] = __float2bfloat16(dv);
      }
    }

    // stage VwT = (ar*v)^T and VwTd = (ar*ratio*v)^T, one b128 write each
    {
      float fw[8], fd[8];
      #pragma unroll
      for (int rep = 0; rep < 8; ++rep) {
        const int   s   = s8 * 8 + rep;
        const float arf = __shfl(arp, s, 64);
        const float dcf = fexp2(L2end - __shfl(L2, s, 64));   // <= 1
        fw[rep] = vpre[rep] * arf;
        fd[rep] = fw[rep] * dcf;
      }
      union { __hip_bfloat162 h2[4]; bf16x8 v; } uw, ud;
      #pragma unroll
      for (int p2 = 0; p2 < 4; ++p2) {
        uw.h2[p2] = __float22bfloat162_rn(make_float2(fw[2*p2], fw[2*p2+1]));
        ud.h2[p2] = __float22bfloat162_rn(make_float2(fd[2*p2], fd[2*p2+1]));
      }
      *(bf16x8*)&VwT [buf][jv][s8 * 8] = uw.v;
      *(bf16x8*)&VwTd[buf][jv][s8 * 8] = ud.v;
    }

    // publish bf16(M)^T for GEMM3 (own i-columns only)
    #pragma unroll
    for (int it = 0; it < 2; ++it)
      #pragma unroll
      for (int jt = 0; jt < 2; ++jt) {
        union { __hip_bfloat162 h2[2]; uint2 u; } pk;
        pk.h2[0] = __float22bfloat162_rn(make_float2(M[it][jt][0], M[it][jt][1]));
        pk.h2[1] = __float22bfloat162_rn(make_float2(M[it][jt][2], M[it][jt][3]));
        *(uint2*)&MhT[buf][jt * 16 + m][w * 32 + it * 16 + quad * 4] = pk.u;
      }

    __syncthreads();   // the ONLY barrier per chunk (drains vmcnt/lgkmcnt)

    // ================= phase B (read buf) =================
    // issue next-chunk prefetch NOW: latency hides under GEMM3/2/4,
    // consumed in next phase A with no intervening barrier.
    #pragma unroll
    for (int ks = 0; ks < 4; ++ks) {
      const float* p = qb + (size_t)(tn + w * 16 + m) * 128 + ks * 32 + quad * 8;
      qpre[ks][0] = *(const float4*)p;
      qpre[ks][1] = *(const float4*)(p + 4);
    }
    #pragma unroll
    for (int rep = 0; rep < 8; ++rep)
      vpre[rep] = vb[(size_t)(tn + s8 * 8 + rep) * 128 + jbase + jv];
    lpre = lb[tn + lane]; apre = ab[tn + lane]; rpre = rb[tn + lane];

    // GEMM3: inter-chunk readout q . bf16(M)
    f32x4 R[2] = {{0.f,0.f,0.f,0.f},{0.f,0.f,0.f,0.f}};
    #pragma unroll
    for (int ks = 0; ks < 4; ++ks)
      #pragma unroll
      for (int jt = 0; jt < 2; ++jt) {
        const bf16x8 mb = *(const bf16x8*)&MhT[buf][jt * 16 + m][ks * 32 + quad * 8];
        R[jt] = MFMA(qf[ks], mb, R[jt]);
      }
    // scale inter part by P_t = exp2(L2_t) (<= 1); intra added unscaled after
    #pragma unroll
    for (int r = 0; r < 4; ++r) {
      const float et = fexp2(tl[r]);
      R[0][r] *= et; R[1][r] *= et;
    }
    // GEMM2: intra-chunk (decay already folded into Sd)
    #pragma unroll
    for (int kk = 0; kk < 2; ++kk) {
      const bf16x8 sa = *(const bf16x8*)&Sd[w][m][kk * 32 + quad * 8];
      #pragma unroll
      for (int jt = 0; jt < 2; ++jt) {
        const bf16x8 vw = *(const bf16x8*)&VwT[buf][jt * 16 + m][kk * 32 + quad * 8];
        R[jt] = MFMA(sa, vw, R[jt]);
      }
    }
    // direct store (wave owns its t-rows: no Rbuf, no reduction)
    #pragma unroll
    for (int jt = 0; jt < 2; ++jt)
      #pragma unroll
      for (int r = 0; r < 4; ++r)
        ob[(size_t)(t0 + w * 16 + quad * 4 + r) * 128 + jbase + jt * 16 + m] =
            R[jt][r];

    // GEMM4: M = exp2(L2_end)*M + K^T (ar*ratio*v)
    const float eend = fexp2(L2end);
    #pragma unroll
    for (int it = 0; it < 2; ++it)
      #pragma unroll
      for (int jt = 0; jt < 2; ++jt)
        #pragma unroll
        for (int r = 0; r < 4; ++r) M[it][jt][r] *= eend;
    #pragma unroll
    for (int kk = 0; kk < 2; ++kk)
      #pragma unroll
      for (int it = 0; it < 2; ++it) {
        const bf16x8 af = cvt8(
            make_float4(k4[kk][it][0], k4[kk][it][1], k4[kk][it][2], k4[kk][it][3]),
            make_float4(k4[kk][it][4], k4[kk][it][5], k4[kk][it][6], k4[kk][it][7]));
        #pragma unroll
        for (int jt = 0; jt < 2; ++jt) {
          const bf16x8 vd = *(const bf16x8*)&VwTd[buf][jt * 16 + m][kk * 32 + quad * 8];
          M[it][jt] = MFMA(af, vd, M[it][jt]);
        }
      }
  }
}

extern "C" void kernel_launch(void* const* d_in, const int* in_sizes, int n_in,
                              void* d_out, int out_size, void* d_ws, size_t ws_size,
                              hipStream_t stream) {
  const float* q  = (const float*)d_in[0];
  const float* k  = (const float*)d_in[1];
  const float* v  = (const float*)d_in[2];
  const float* a  = (const float*)d_in[3];
  const float* r  = (const float*)d_in[4];
  const float* l  = (const float*)d_in[5];
  const float* m0 = (const float*)d_in[6];
  float* out = (float*)d_out;

  dim3 grid(NSPLIT, B_);
  lmm_ct64<<<grid, 256, 0, stream>>>(q, k, v, a, r, l, m0, out);
}

// Round 3
// 311.279 us; speedup vs baseline: 1.3569x; 1.2748x over previous
//
#include <hip/hip_runtime.h>
#include <hip/hip_bf16.h>

// LatentMatrixMemory: M_t = lam*M + (rho*alpha)*(k outer v); r_t = q^T M_t
// B=64, T=2048, DK=DV=128, fp32 in/out. Threshold permits bf16 compute.
//
// Round 5 (resubmit after infra failure; logic re-audited for hang/fault):
//  - k staged one chunk AHEAD via __builtin_amdgcn_global_load_lds (zero VGPR,
//    async) into a double-buffered fp32 LDS tile [64][128], 16B-block
//    XOR-swizzled (blk ^= row&7) to make GEMM1's ds_read_b128 conflict-free.
//    Swizzle is applied on the *global source* lane address (LDS dest must be
//    lane-linear for global_load_lds) and undone on every read.
//  - Two barriers/chunk: loop-top drains the prefetch (klds[buf] ready),
//    mid-chunk publishes VwT/VwTd/MhT (single-buffered: WAR separated by
//    the loop-top barrier).
//  - q/v/lam/alpha/rho stay register-prefetched, issued top of phase B ->
//    a full phase of slack before consumption.
//  - XCD-chunked block swizzle: all 4 DV-splits of a batch land on one XCD,
//    so shared k/q rows are fetched from HBM once per XCD, not 4x.
// Grid: 4 DV-splits x 64 batches = 256 blocks; block = 4 waves, 1 block/CU.

typedef float  f32x4  __attribute__((ext_vector_type(4)));
typedef short  bf16x8 __attribute__((ext_vector_type(8)));

constexpr int B_ = 64, T_ = 2048;
constexpr int NSPLIT = 4;
constexpr int CT = 64;          // chunk length
constexpr int NCH = T_ / CT;    // 32 chunks

__device__ __forceinline__ bf16x8 cvt8(float4 a, float4 b) {
  union { __hip_bfloat162 h2[4]; bf16x8 v; } u;
  u.h2[0] = __float22bfloat162_rn(make_float2(a.x, a.y));
  u.h2[1] = __float22bfloat162_rn(make_float2(a.z, a.w));
  u.h2[2] = __float22bfloat162_rn(make_float2(b.x, b.y));
  u.h2[3] = __float22bfloat162_rn(make_float2(b.z, b.w));
  return u.v;
}

__device__ __forceinline__ float fexp2(float x) { return __builtin_exp2f(x); }
__device__ __forceinline__ float flog2(float x) { return __builtin_log2f(x); }

#define MFMA(a, b, c) __builtin_amdgcn_mfma_f32_16x16x32_bf16((a), (b), (c), 0, 0, 0)

__device__ __forceinline__ void gload16(const float* gsrc, float* ldst) {
  __builtin_amdgcn_global_load_lds(
      (const __attribute__((address_space(1))) void*)gsrc,
      (__attribute__((address_space(3))) void*)ldst, 16, 0, 0);
}

__global__ __launch_bounds__(256, 1) void lmm_ct64p(
    const float* __restrict__ q_g, const float* __restrict__ k_g,
    const float* __restrict__ v_g, const float* __restrict__ a_g,
    const float* __restrict__ r_g, const float* __restrict__ l_g,
    const float* __restrict__ m0_g, float* __restrict__ out_g)
{
  // XCD-chunked bijective swizzle: 256 blocks = 8 XCD x (8 batches x 4 splits).
  // All 4 splits of a batch share an XCD -> k/q rows hit that XCD's L2.
  const int bid   = blockIdx.y * NSPLIT + blockIdx.x;   // dispatch-linear
  const int b     = (bid & 7) * 8 + (bid >> 5);
  const int split = (bid >> 3) & 3;

  const int tid   = threadIdx.x;
  const int w     = tid >> 6;        // wave 0..3
  const int lane  = tid & 63;
  const int m     = lane & 15;       // MFMA row/col-in-tile
  const int quad  = lane >> 4;
  const int jbase = split * 32;

  // k tile, fp32, double-buffered, 16B-block swizzled: physical block
  // (row, p) holds logical (row, p ^ (row&7)). 64 KiB.
  __shared__ __align__(16) float klds[2][64][128];
  // single-buffered cross-wave staging (WAR separated by loop-top barrier):
  __shared__ __align__(16) __hip_bfloat16 MhT [32][136]; // bf16(M)^T [j][i]
  __shared__ __align__(16) __hip_bfloat16 VwT [32][72];  // (ar*v)^T  [j][s]
  __shared__ __align__(16) __hip_bfloat16 VwTd[32][72];  // (ar*ratio*v)^T
  // wave-private:
  __shared__ __align__(16) __hip_bfloat16 Sd[4][16][72]; // decayed scores [t][s]

  const float* qb = q_g + (size_t)b * T_ * 128;
  const float* kb = k_g + (size_t)b * T_ * 128;
  const float* vb = v_g + (size_t)b * T_ * 128;
  const float* ab = a_g + (size_t)b * T_;
  const float* rb = r_g + (size_t)b * T_;
  const float* lb = l_g + (size_t)b * T_;
  float*       ob = out_g + (size_t)b * T_ * 128;

  // ---- M accumulator (fp32 resident): rows w*32..+32, cols jbase..+32 ----
  f32x4 M[2][2];
  #pragma unroll
  for (int it = 0; it < 2; ++it)
    #pragma unroll
    for (int jt = 0; jt < 2; ++jt)
      #pragma unroll
      for (int r = 0; r < 4; ++r)
        M[it][jt][r] =
            m0_g[((size_t)b * 128 + w * 32 + it * 16 + quad * 4 + r) * 128 +
                 jbase + jt * 16 + m];

  // ---- prefetch lane mappings ----
  const int jv   = tid & 31;   // V staging column
  const int s8   = tid >> 5;   // V staging 8-row s-block
  const int prow = lane >> 5;  // k-DMA: row parity within 1 KiB call
  const int pblk = lane & 31;  // k-DMA: 16B block within row pair

  float4 qpre[4][2];
  float  vpre[8];
  float  lpre, apre, rpre;

  // ---- chunk-0 prefetch (drained by first loop-top barrier) ----
  lpre = lb[lane]; apre = ab[lane]; rpre = rb[lane];
  #pragma unroll
  for (int c = 0; c < 8; ++c) {      // wave w stages k rows [16w, 16w+16)
    const int row = w * 16 + c * 2 + prow;
    gload16(kb + (size_t)row * 128 + ((pblk ^ (row & 7)) << 2),
            &klds[0][w * 16 + c * 2][0]);
  }
  #pragma unroll
  for (int ks = 0; ks < 4; ++ks) {
    const float* p = qb + (size_t)(w * 16 + m) * 128 + ks * 32 + quad * 8;
    qpre[ks][0] = *(const float4*)p;
    qpre[ks][1] = *(const float4*)(p + 4);
  }
  #pragma unroll
  for (int rep = 0; rep < 8; ++rep)
    vpre[rep] = vb[(size_t)(s8 * 8 + rep) * 128 + jbase + jv];

  #pragma unroll 2
  for (int ch = 0; ch < NCH; ++ch) {
    const int t0   = ch * CT;
    const int tn   = (ch + 1 < NCH) ? t0 + CT : t0;  // clamped prefetch base
    const int buf  = ch & 1;
    const int nbuf = buf ^ 1;

    __syncthreads();  // B1: drains prefetch -> klds[buf]/regs valid; WAR on VwT/MhT

    // ================= phase A =================
    // decay prefix in log2 space (redundant 64-lane scan per wave)
    float x = flog2(fmaxf(lpre, 1e-20f));
    #pragma unroll
    for (int d = 1; d < 64; d <<= 1) {
      const float o = __shfl_up(x, d, 64);
      if (lane >= d) x += o;
    }
    const float L2    = x;
    const float L2end = __shfl(L2, 63, 64);
    const float arp   = apre * rpre;     // capture before phase-B overwrite

    bf16x8 qf[4];
    #pragma unroll
    for (int ks = 0; ks < 4; ++ks) qf[ks] = cvt8(qpre[ks][0], qpre[ks][1]);

    // GEMM1: S[own 16 t][64 s], k from swizzled LDS (conflict-free b128)
    f32x4 S[4] = {{0.f,0.f,0.f,0.f},{0.f,0.f,0.f,0.f},
                  {0.f,0.f,0.f,0.f},{0.f,0.f,0.f,0.f}};
    #pragma unroll
    for (int sb = 0; sb < 4; ++sb) {
      const int rowk = sb * 16 + m;
      const int xk   = rowk & 7;
      #pragma unroll
      for (int ks = 0; ks < 4; ++ks) {
        const int bk0 = ks * 8 + quad * 2;
        const float4 kA = *(const float4*)&klds[buf][rowk][((bk0      ^ xk) << 2)];
        const float4 kB = *(const float4*)&klds[buf][rowk][(((bk0 + 1) ^ xk) << 2)];
        S[sb] = MFMA(qf[ks], cvt8(kA, kB), S[sb]);
      }
    }

    // decay + causal mask -> Sd (wave-private)
    const int tl0 = w * 16 + quad * 4;
    float tl[4];
    #pragma unroll
    for (int r = 0; r < 4; ++r) tl[r] = __shfl(L2, tl0 + r, 64);
    #pragma unroll
    for (int sb = 0; sb < 4; ++sb) {
      const int   sl_i = sb * 16 + m;
      const float sl   = __shfl(L2, sl_i, 64);
      #pragma unroll
      for (int r = 0; r < 4; ++r) {
        const float dv = (sl_i <= tl0 + r) ? S[sb][r] * fexp2(tl[r] - sl) : 0.f;
        Sd[w][quad * 4 + r][sl_i] = __float2bfloat16(dv);
      }
    }

    // stage VwT = (ar*v)^T and VwTd = (ar*ratio*v)^T
    {
      float fw[8], fd[8];
      #pragma unroll
      for (int rep = 0; rep < 8; ++rep) {
        const int   s   = s8 * 8 + rep;
        const float arf = __shfl(arp, s, 64);
        const float dcf = fexp2(L2end - __shfl(L2, s, 64));   // <= 1
        fw[rep] = vpre[rep] * arf;
        fd[rep] = fw[rep] * dcf;
      }
      union { __hip_bfloat162 h2[4]; bf16x8 v; } uw, ud;
      #pragma unroll
      for (int p2 = 0; p2 < 4; ++p2) {
        uw.h2[p2] = __float22bfloat162_rn(make_float2(fw[2*p2], fw[2*p2+1]));
        ud.h2[p2] = __float22bfloat162_rn(make_float2(fd[2*p2], fd[2*p2+1]));
      }
      *(bf16x8*)&VwT [jv][s8 * 8] = uw.v;
      *(bf16x8*)&VwTd[jv][s8 * 8] = ud.v;
    }

    // publish bf16(M)^T for GEMM3
    #pragma unroll
    for (int it = 0; it < 2; ++it)
      #pragma unroll
      for (int jt = 0; jt < 2; ++jt) {
        union { __hip_bfloat162 h2[2]; uint2 u; } pk;
        pk.h2[0] = __float22bfloat162_rn(make_float2(M[it][jt][0], M[it][jt][1]));
        pk.h2[1] = __float22bfloat162_rn(make_float2(M[it][jt][2], M[it][jt][3]));
        *(uint2*)&MhT[jt * 16 + m][w * 32 + it * 16 + quad * 4] = pk.u;
      }

    __syncthreads();  // B2: VwT/VwTd/MhT visible (phase A issued no vmem)

    // ================= phase B =================
    // next-chunk prefetch: async k DMA + register q/v/scalars.
    // A full phase (~GEMM3/2/4) of slack before the B1 drain consumes them.
    lpre = lb[tn + lane]; apre = ab[tn + lane]; rpre = rb[tn + lane];
    #pragma unroll
    for (int c = 0; c < 8; ++c) {
      const int row = w * 16 + c * 2 + prow;
      gload16(kb + (size_t)(tn + row) * 128 + ((pblk ^ (row & 7)) << 2),
              &klds[nbuf][w * 16 + c * 2][0]);
    }
    #pragma unroll
    for (int ks = 0; ks < 4; ++ks) {
      const float* p = qb + (size_t)(tn + w * 16 + m) * 128 + ks * 32 + quad * 8;
      qpre[ks][0] = *(const float4*)p;
      qpre[ks][1] = *(const float4*)(p + 4);
    }
    #pragma unroll
    for (int rep = 0; rep < 8; ++rep)
      vpre[rep] = vb[(size_t)(tn + s8 * 8 + rep) * 128 + jbase + jv];

    // GEMM3: inter-chunk readout q . bf16(M)
    f32x4 R[2] = {{0.f,0.f,0.f,0.f},{0.f,0.f,0.f,0.f}};
    #pragma unroll
    for (int ks = 0; ks < 4; ++ks)
      #pragma unroll
      for (int jt = 0; jt < 2; ++jt) {
        const bf16x8 mb = *(const bf16x8*)&MhT[jt * 16 + m][ks * 32 + quad * 8];
        R[jt] = MFMA(qf[ks], mb, R[jt]);
      }
    #pragma unroll
    for (int r = 0; r < 4; ++r) {
      const float et = fexp2(tl[r]);     // P_t <= 1
      R[0][r] *= et; R[1][r] *= et;
    }
    // GEMM2: intra-chunk (decay folded into Sd)
    #pragma unroll
    for (int kk = 0; kk < 2; ++kk) {
      const bf16x8 sa = *(const bf16x8*)&Sd[w][m][kk * 32 + quad * 8];
      #pragma unroll
      for (int jt = 0; jt < 2; ++jt) {
        const bf16x8 vw = *(const bf16x8*)&VwT[jt * 16 + m][kk * 32 + quad * 8];
        R[jt] = MFMA(sa, vw, R[jt]);
      }
    }
    // direct store (wave owns its t-rows)
    #pragma unroll
    for (int jt = 0; jt < 2; ++jt)
      #pragma unroll
      for (int r = 0; r < 4; ++r)
        ob[(size_t)(t0 + w * 16 + quad * 4 + r) * 128 + jbase + jt * 16 + m] =
            R[jt][r];

    // GEMM4: M = exp2(L2_end)*M + K^T (ar*ratio*v); k read transposed from LDS
    const float eend = fexp2(L2end);
    #pragma unroll
    for (int it = 0; it < 2; ++it)
      #pragma unroll
      for (int jt = 0; jt < 2; ++jt)
        #pragma unroll
        for (int r = 0; r < 4; ++r) M[it][jt][r] *= eend;
    #pragma unroll
    for (int kk = 0; kk < 2; ++kk)
      #pragma unroll
      for (int it = 0; it < 2; ++it) {
        float kv[8];
        #pragma unroll
        for (int u = 0; u < 8; ++u) {
          const int rows = kk * 32 + quad * 8 + u;
          const int col  = w * 32 + it * 16 + m;
          kv[u] = klds[buf][rows][(((col >> 2) ^ (rows & 7)) << 2) | (col & 3)];
        }
        const bf16x8 af = cvt8(make_float4(kv[0], kv[1], kv[2], kv[3]),
                               make_float4(kv[4], kv[5], kv[6], kv[7]));
        #pragma unroll
        for (int jt = 0; jt < 2; ++jt) {
          const bf16x8 vd = *(const bf16x8*)&VwTd[jt * 16 + m][kk * 32 + quad * 8];
          M[it][jt] = MFMA(af, vd, M[it][jt]);
        }
      }
  }
}

extern "C" void kernel_launch(void* const* d_in, const int* in_sizes, int n_in,
                              void* d_out, int out_size, void* d_ws, size_t ws_size,
                              hipStream_t stream) {
  const float* q  = (const float*)d_in[0];
  const float* k  = (const float*)d_in[1];
  const float* v  = (const float*)d_in[2];
  const float* a  = (const float*)d_in[3];
  const float* r  = (const float*)d_in[4];
  const float* l  = (const float*)d_in[5];
  const float* m0 = (const float*)d_in[6];
  float* out = (float*)d_out;

  dim3 grid(NSPLIT, B_);
  lmm_ct64p<<<grid, 256, 0, stream>>>(q, k, v, a, r, l, m0, out);
}